// Round 1
// baseline (73.972 us; speedup 1.0000x reference)
//
#include <hip/hip_runtime.h>

#define TILE 32
#define HALO 5
#define SM_W 42      // TILE + 2*HALO
#define SM_STRIDE 44 // padded LDS row stride
#define BATCH 16
#define CH 3
#define H 512
#define W 512
#define NTILE 16     // 512/32
#define NBLOCKS (BATCH * NTILE * NTILE) // 4096

__global__ __launch_bounds__(256) void ssim_tile_kernel(
    const float* __restrict__ pred, const float* __restrict__ gt,
    float* __restrict__ partial)
{
    __shared__ float sm[5][SM_W][SM_STRIDE];
    __shared__ float red[4];

    const int tid = threadIdx.x;
    const int bid = blockIdx.x;
    const int b  = bid >> 8;
    const int ty = (bid >> 4) & 15;
    const int tx = bid & 15;
    const int y0 = ty * TILE - HALO;
    const int x0 = tx * TILE - HALO;

    // ---- Stage 1: load halo tile, reduce over channels into 5 LDS planes ----
    for (int idx = tid; idx < SM_W * SM_W; idx += 256) {
        const int ly = idx / SM_W;
        const int lx = idx - ly * SM_W;
        const int gy = y0 + ly;
        const int gx = x0 + lx;
        float sp = 0.f, sg = 0.f, spp = 0.f, sgg = 0.f, spg = 0.f;
        if (gy >= 0 && gy < H && gx >= 0 && gx < W) {
            const size_t base = ((size_t)b * CH) * H * W + (size_t)gy * W + gx;
            #pragma unroll
            for (int c = 0; c < CH; ++c) {
                const float p = pred[base + (size_t)c * H * W];
                const float g = gt  [base + (size_t)c * H * W];
                sp  += p;     sg  += g;
                spp += p * p; sgg += g * g; spg += p * g;
            }
        }
        sm[0][ly][lx] = sp;
        sm[1][ly][lx] = sg;
        sm[2][ly][lx] = spp;
        sm[3][ly][lx] = sgg;
        sm[4][ly][lx] = spg;
    }
    __syncthreads();

    // ---- Stage 2: horizontal 11-tap box sums (42 rows x 32 cols) -> regs ----
    float hreg[6][5];
    #pragma unroll
    for (int k = 0; k < 6; ++k) {
        const int idx = tid + k * 256;
        if (idx < SM_W * TILE) {
            const int hy = idx >> 5;
            const int hx = idx & 31;
            #pragma unroll
            for (int q = 0; q < 5; ++q) {
                float s = 0.f;
                #pragma unroll
                for (int j = 0; j < 11; ++j) s += sm[q][hy][hx + j];
                hreg[k][q] = s;
            }
        }
    }
    __syncthreads();
    // write back into the same LDS planes (cols 0..31 of each row)
    #pragma unroll
    for (int k = 0; k < 6; ++k) {
        const int idx = tid + k * 256;
        if (idx < SM_W * TILE) {
            const int hy = idx >> 5;
            const int hx = idx & 31;
            #pragma unroll
            for (int q = 0; q < 5; ++q) sm[q][hy][hx] = hreg[k][q];
        }
    }
    __syncthreads();

    // ---- Stage 3: vertical 11-tap + SSIM per output pixel ----
    const float inv_n   = 1.0f / 363.0f;   // N = C*K*K
    const float inv_nm1 = 1.0f / 362.0f;   // unbiased var divisor
    const float c1 = 0.0001f;              // 0.01^2
    const float c2 = 0.0009f;              // 0.03^2
    float local = 0.f;
    #pragma unroll
    for (int k = 0; k < 4; ++k) {
        const int idx = tid + k * 256;     // 0..1023, exactly 32x32
        const int oy = idx >> 5;
        const int ox = idx & 31;
        float s0 = 0.f, s1 = 0.f, s2 = 0.f, s3 = 0.f, s4 = 0.f;
        #pragma unroll
        for (int j = 0; j < 11; ++j) {
            s0 += sm[0][oy + j][ox];
            s1 += sm[1][oy + j][ox];
            s2 += sm[2][oy + j][ox];
            s3 += sm[3][oy + j][ox];
            s4 += sm[4][oy + j][ox];
        }
        const float mu_p  = s0 * inv_n;
        const float mu_g  = s1 * inv_n;
        const float var_p = (s2 - s0 * mu_p) * inv_nm1;
        const float var_g = (s3 - s1 * mu_g) * inv_nm1;
        const float cov   = (s4 - s0 * mu_g) * inv_n;
        const float num = (2.f * mu_p * mu_g + c1) * (2.f * cov + c2);
        const float den = (mu_p * mu_p + mu_g * mu_g + c1) * (var_p + var_g + c2);
        local += num / (den + 1e-8f);
    }

    // ---- Stage 4: block reduce (wave64 shuffle -> LDS -> partial) ----
    #pragma unroll
    for (int off = 32; off > 0; off >>= 1) local += __shfl_down(local, off);
    if ((tid & 63) == 0) red[tid >> 6] = local;
    __syncthreads();
    if (tid == 0) partial[bid] = red[0] + red[1] + red[2] + red[3];
}

__global__ __launch_bounds__(256) void ssim_final_reduce(
    const float* __restrict__ partial, float* __restrict__ out)
{
    __shared__ float red[4];
    const int tid = threadIdx.x;
    float s = 0.f;
    for (int i = tid; i < NBLOCKS; i += 256) s += partial[i];
    #pragma unroll
    for (int off = 32; off > 0; off >>= 1) s += __shfl_down(s, off);
    if ((tid & 63) == 0) red[tid >> 6] = s;
    __syncthreads();
    if (tid == 0) {
        const float total = red[0] + red[1] + red[2] + red[3];
        out[0] = 1.0f - total * (1.0f / (float)(BATCH * H * W)); // / 2^22, exact
    }
}

extern "C" void kernel_launch(void* const* d_in, const int* in_sizes, int n_in,
                              void* d_out, int out_size, void* d_ws, size_t ws_size,
                              hipStream_t stream) {
    const float* pred = (const float*)d_in[0];
    const float* gt   = (const float*)d_in[1];
    float* out        = (float*)d_out;
    float* partial    = (float*)d_ws;   // NBLOCKS floats, fully overwritten each call

    ssim_tile_kernel<<<NBLOCKS, 256, 0, stream>>>(pred, gt, partial);
    ssim_final_reduce<<<1, 256, 0, stream>>>(partial, out);
}

// Round 2
// 55.387 us; speedup vs baseline: 1.3356x; 1.3356x over previous
//
#include <hip/hip_runtime.h>

#define TILE 32
#define HALO 5
#define SM_W 42       // TILE + 2*HALO
#define RAW_STRIDE 44 // padded row stride for raw planes (16B-aligned rows)
#define HS_STRIDE 64  // transposed hsum plane stride (room for 4-float XOR swizzle)
#define BATCH 16
#define CH 3
#define H 512
#define W 512
#define NTILE 16
#define NBLOCKS (BATCH * NTILE * NTILE) // 4096

__global__ __launch_bounds__(256) void ssim_tile_kernel(
    const float* __restrict__ pred, const float* __restrict__ gt,
    float* __restrict__ partial)
{
    // raw: 5 channel-reduced planes of the 42x42 halo tile (36.96 KB)
    // hsT: horizontal box sums, TRANSPOSED [x][y] with 4-float XOR swizzle (40 KB)
    __shared__ __align__(16) float raw[5][SM_W][RAW_STRIDE];
    __shared__ __align__(16) float hsT[5][TILE][HS_STRIDE];
    __shared__ float red[4];

    const int tid = threadIdx.x;
    // XCD-chunked swizzle: 8 XCDs, 4096 blocks -> contiguous chunks of 512 per XCD
    const int bid = (blockIdx.x & 7) * (NBLOCKS / 8) + (blockIdx.x >> 3);
    const int b  = bid >> 8;
    const int ty = (bid >> 4) & 15;
    const int tx = bid & 15;
    const int y0 = ty * TILE - HALO;
    const int x0 = tx * TILE - HALO;

    // ---- Stage 1: load halo tile (coalesced b32), channel-reduce into 5 planes
    for (int idx = tid; idx < SM_W * SM_W; idx += 256) {
        const int ly = idx / SM_W;
        const int lx = idx - ly * SM_W;
        const int gy = y0 + ly;
        const int gx = x0 + lx;
        float sp = 0.f, sg = 0.f, spp = 0.f, sgg = 0.f, spg = 0.f;
        if ((unsigned)gy < H && (unsigned)gx < W) {
            const size_t base = ((size_t)b * CH) * (H * W) + (size_t)gy * W + gx;
            #pragma unroll
            for (int c = 0; c < CH; ++c) {
                const float p = pred[base + (size_t)c * (H * W)];
                const float g = gt  [base + (size_t)c * (H * W)];
                sp += p; sg += g;
                spp = fmaf(p, p, spp); sgg = fmaf(g, g, sgg); spg = fmaf(p, g, spg);
            }
        }
        raw[0][ly][lx] = sp;  raw[1][ly][lx] = sg;
        raw[2][ly][lx] = spp; raw[3][ly][lx] = sgg; raw[4][ly][lx] = spg;
    }
    __syncthreads();

    // ---- Stage 2: horizontal 11-tap via sliding window, 8-px runs.
    // 168 tasks: r = row 0..41, run = 0..3 (cols run*8 .. run*8+7).
    // Reads: 5 aligned float4 per plane (cols xc..xc+19). Writes transposed+swizzled.
    if (tid < SM_W * 4) {
        const int r   = tid % SM_W;       // consecutive lanes -> consecutive rows
        const int run = tid / SM_W;
        const int xc  = run * 8;
        #pragma unroll
        for (int q = 0; q < 5; ++q) {
            float rr[20];
            #pragma unroll
            for (int k = 0; k < 5; ++k) {
                const float4 v = *(const float4*)&raw[q][r][xc + 4 * k];
                rr[4*k+0] = v.x; rr[4*k+1] = v.y; rr[4*k+2] = v.z; rr[4*k+3] = v.w;
            }
            float s = rr[0];
            #pragma unroll
            for (int j = 1; j < 11; ++j) s += rr[j];
            float hv[8];
            hv[0] = s;
            #pragma unroll
            for (int j = 1; j < 8; ++j) { s += rr[10 + j] - rr[j - 1]; hv[j] = s; }
            // transposed store: element (x=xc+j, y=r) at y' = r ^ ((x&7)<<2); x&7 == j
            #pragma unroll
            for (int j = 0; j < 8; ++j) hsT[q][xc + j][r ^ (j << 2)] = hv[j];
        }
    }
    __syncthreads();

    // ---- Stage 3: vertical 11-tap via sliding window, 4-row runs per thread.
    // Thread t: x = t&31, rows y0r..y0r+3. Column reads are contiguous float4s
    // (swizzle on 4-row block index keeps them conflict-free: banks = 4*(blk^x&7)).
    const int x   = tid & 31;
    const int yr  = tid >> 5;     // 0..7
    const int xs  = x & 7;
    float ss[5][4];
    #pragma unroll
    for (int q = 0; q < 5; ++q) {
        float v[16];
        #pragma unroll
        for (int m = 0; m < 4; ++m) {
            const int yblk = (yr + m) ^ xs;
            const float4 u = *(const float4*)&hsT[q][x][4 * yblk];
            v[4*m+0] = u.x; v[4*m+1] = u.y; v[4*m+2] = u.z; v[4*m+3] = u.w;
        }
        float s = v[0];
        #pragma unroll
        for (int j = 1; j < 11; ++j) s += v[j];
        ss[q][0] = s;
        #pragma unroll
        for (int k = 1; k < 4; ++k) { s += v[10 + k] - v[k - 1]; ss[q][k] = s; }
    }

    // ---- SSIM for the 4 pixels
    const float inv_n   = 1.0f / 363.0f;
    const float inv_nm1 = 1.0f / 362.0f;
    const float c1 = 1e-4f, c2 = 9e-4f;
    float local = 0.f;
    #pragma unroll
    for (int k = 0; k < 4; ++k) {
        const float s0 = ss[0][k], s1 = ss[1][k], s2 = ss[2][k], s3 = ss[3][k], s4 = ss[4][k];
        const float mu_p  = s0 * inv_n;
        const float mu_g  = s1 * inv_n;
        const float var_p = (s2 - s0 * mu_p) * inv_nm1;
        const float var_g = (s3 - s1 * mu_g) * inv_nm1;
        const float cov   = (s4 - s0 * mu_g) * inv_n;
        const float num = (2.f * mu_p * mu_g + c1) * (2.f * cov + c2);
        const float den = (mu_p * mu_p + mu_g * mu_g + c1) * (var_p + var_g + c2);
        local += num / (den + 1e-8f);
    }

    // ---- Block reduce
    #pragma unroll
    for (int off = 32; off > 0; off >>= 1) local += __shfl_down(local, off);
    if ((tid & 63) == 0) red[tid >> 6] = local;
    __syncthreads();
    if (tid == 0) partial[bid] = red[0] + red[1] + red[2] + red[3];
}

__global__ __launch_bounds__(256) void ssim_final_reduce(
    const float* __restrict__ partial, float* __restrict__ out)
{
    __shared__ float red[4];
    const int tid = threadIdx.x;
    float s = 0.f;
    for (int i = tid; i < NBLOCKS; i += 256) s += partial[i];
    #pragma unroll
    for (int off = 32; off > 0; off >>= 1) s += __shfl_down(s, off);
    if ((tid & 63) == 0) red[tid >> 6] = s;
    __syncthreads();
    if (tid == 0) {
        const float total = red[0] + red[1] + red[2] + red[3];
        out[0] = 1.0f - total * (1.0f / (float)(BATCH * H * W));
    }
}

extern "C" void kernel_launch(void* const* d_in, const int* in_sizes, int n_in,
                              void* d_out, int out_size, void* d_ws, size_t ws_size,
                              hipStream_t stream) {
    const float* pred = (const float*)d_in[0];
    const float* gt   = (const float*)d_in[1];
    float* out        = (float*)d_out;
    float* partial    = (float*)d_ws;

    ssim_tile_kernel<<<NBLOCKS, 256, 0, stream>>>(pred, gt, partial);
    ssim_final_reduce<<<1, 256, 0, stream>>>(partial, out);
}

// Round 3
// 44.017 us; speedup vs baseline: 1.6805x; 1.2583x over previous
//
#include <hip/hip_runtime.h>

#define TILE 32
#define HALO 5
#define SM_W 42      // TILE + 2*HALO rows/cols of raw halo data
#define AB_STR 46    // float2 stride: 92 floats = 28 mod 32 banks -> full bank-quad rotation
#define E_STR 44     // float stride: 12 mod 32 banks -> full bank-quad rotation
#define BATCH 16
#define CH 3
#define H 512
#define W 512
#define NBLOCKS 4096

__global__ __launch_bounds__(256, 4) void ssim_tile_kernel(
    const float* __restrict__ pred, const float* __restrict__ gt,
    float* __restrict__ partial)
{
    // Raw channel-reduced planes over the 42x42 halo tile; after stage 2 the
    // SAME memory is reused as transposed h-sum planes [x=0..31][yidx=0..41].
    __shared__ __align__(16) float2 ab[SM_W][AB_STR];  // (sum p, sum g)      15.5 KB
    __shared__ __align__(16) float2 cd[SM_W][AB_STR];  // (sum p^2, sum g^2)  15.5 KB
    __shared__ __align__(16) float  ee[SM_W][E_STR];   // sum p*g              7.4 KB
    __shared__ float red[4];

    const int tid = threadIdx.x;
    const int bid = (blockIdx.x & 7) * (NBLOCKS / 8) + (blockIdx.x >> 3); // XCD chunks
    const int b  = bid >> 8;
    const int ty = (bid >> 4) & 15;
    const int tx = bid & 15;
    const int y0 = ty * TILE - HALO;   // global row of local row 0
    const int x0 = tx * TILE - HALO;   // global col of local col 0

    const float* __restrict__ pb = pred + (size_t)b * (CH * H * W);
    const float* __restrict__ gb = gt   + (size_t)b * (CH * H * W);

    // ---- Stage 1: load halo tile once, channel-reduce 5 quantities ----
    for (int idx = tid; idx < SM_W * SM_W; idx += 256) {
        const int ly = idx / SM_W;
        const int lx = idx - ly * SM_W;
        const int gy = y0 + ly;
        const int gx = x0 + lx;
        float sp = 0.f, sg = 0.f, spp = 0.f, sgg = 0.f, spg = 0.f;
        if ((unsigned)gy < H && (unsigned)gx < W) {
            const int base = gy * W + gx;
            #pragma unroll
            for (int c = 0; c < CH; ++c) {
                const float p = pb[base + c * (H * W)];
                const float g = gb[base + c * (H * W)];
                sp += p; sg += g;
                spp = fmaf(p, p, spp); sgg = fmaf(g, g, sgg); spg = fmaf(p, g, spg);
            }
        }
        ab[ly][lx] = make_float2(sp, sg);
        cd[ly][lx] = make_float2(spp, sgg);
        ee[ly][lx] = spg;
    }
    __syncthreads();

    // ---- Stage 2: horizontal 11-tap sliding sums, held in registers ----
    // 168 tasks: r = 0..41 (consecutive lanes -> consecutive rows), run = 0..3.
    // Outputs local cols 8run..8run+7; window needs local cols [8run, 8run+17].
    float2 hvab[8], hvcd[8];
    float  hve[8];
    int r = 0, c0 = 0;
    if (tid < SM_W * 4) {
        r  = tid % SM_W;
        c0 = (tid / SM_W) * 8;
        {   // (sp,sg) plane
            float2 v[20];
            #pragma unroll
            for (int k = 0; k < 10; ++k) {
                const float4 u = *(const float4*)&ab[r][c0 + 2 * k];
                v[2*k] = make_float2(u.x, u.y); v[2*k+1] = make_float2(u.z, u.w);
            }
            float sx = v[0].x, sy = v[0].y;
            #pragma unroll
            for (int j = 1; j < 11; ++j) { sx += v[j].x; sy += v[j].y; }
            hvab[0] = make_float2(sx, sy);
            #pragma unroll
            for (int j = 1; j < 8; ++j) {
                sx += v[10 + j].x - v[j - 1].x;
                sy += v[10 + j].y - v[j - 1].y;
                hvab[j] = make_float2(sx, sy);
            }
        }
        {   // (pp,gg) plane
            float2 v[20];
            #pragma unroll
            for (int k = 0; k < 10; ++k) {
                const float4 u = *(const float4*)&cd[r][c0 + 2 * k];
                v[2*k] = make_float2(u.x, u.y); v[2*k+1] = make_float2(u.z, u.w);
            }
            float sx = v[0].x, sy = v[0].y;
            #pragma unroll
            for (int j = 1; j < 11; ++j) { sx += v[j].x; sy += v[j].y; }
            hvcd[0] = make_float2(sx, sy);
            #pragma unroll
            for (int j = 1; j < 8; ++j) {
                sx += v[10 + j].x - v[j - 1].x;
                sy += v[10 + j].y - v[j - 1].y;
                hvcd[j] = make_float2(sx, sy);
            }
        }
        {   // pg plane
            float v[20];
            #pragma unroll
            for (int k = 0; k < 5; ++k) {
                const float4 u = *(const float4*)&ee[r][c0 + 4 * k];
                v[4*k] = u.x; v[4*k+1] = u.y; v[4*k+2] = u.z; v[4*k+3] = u.w;
            }
            float s = v[0];
            #pragma unroll
            for (int j = 1; j < 11; ++j) s += v[j];
            hve[0] = s;
            #pragma unroll
            for (int j = 1; j < 8; ++j) { s += v[10 + j] - v[j - 1]; hve[j] = s; }
        }
    }
    __syncthreads();
    // write back TRANSPOSED into the same planes: [x][yidx] ; x<32<42, yidx<42<46
    if (tid < SM_W * 4) {
        #pragma unroll
        for (int j = 0; j < 8; ++j) {
            ab[c0 + j][r] = hvab[j];
            cd[c0 + j][r] = hvcd[j];
            ee[c0 + j][r] = hve[j];
        }
    }
    __syncthreads();

    // ---- Stage 3: vertical 11-tap sliding sums + SSIM, 4 rows per thread ----
    const int x  = tid & 31;
    const int yr = tid >> 5;   // rows 4yr .. 4yr+3; window yidx [4yr, 4yr+13]
    float2 sab[4], scd[4];
    float  se[4];
    {
        float2 v[16];
        #pragma unroll
        for (int k = 0; k < 8; ++k) {
            const float4 u = *(const float4*)&ab[x][4 * yr + 2 * k];
            v[2*k] = make_float2(u.x, u.y); v[2*k+1] = make_float2(u.z, u.w);
        }
        float sx = v[0].x, sy = v[0].y;
        #pragma unroll
        for (int j = 1; j < 11; ++j) { sx += v[j].x; sy += v[j].y; }
        sab[0] = make_float2(sx, sy);
        #pragma unroll
        for (int k = 1; k < 4; ++k) {
            sx += v[10 + k].x - v[k - 1].x;
            sy += v[10 + k].y - v[k - 1].y;
            sab[k] = make_float2(sx, sy);
        }
    }
    {
        float2 v[16];
        #pragma unroll
        for (int k = 0; k < 8; ++k) {
            const float4 u = *(const float4*)&cd[x][4 * yr + 2 * k];
            v[2*k] = make_float2(u.x, u.y); v[2*k+1] = make_float2(u.z, u.w);
        }
        float sx = v[0].x, sy = v[0].y;
        #pragma unroll
        for (int j = 1; j < 11; ++j) { sx += v[j].x; sy += v[j].y; }
        scd[0] = make_float2(sx, sy);
        #pragma unroll
        for (int k = 1; k < 4; ++k) {
            sx += v[10 + k].x - v[k - 1].x;
            sy += v[10 + k].y - v[k - 1].y;
            scd[k] = make_float2(sx, sy);
        }
    }
    {
        float v[16];
        #pragma unroll
        for (int k = 0; k < 4; ++k) {
            const float4 u = *(const float4*)&ee[x][4 * yr + 4 * k];
            v[4*k] = u.x; v[4*k+1] = u.y; v[4*k+2] = u.z; v[4*k+3] = u.w;
        }
        float s = v[0];
        #pragma unroll
        for (int j = 1; j < 11; ++j) s += v[j];
        se[0] = s;
        #pragma unroll
        for (int k = 1; k < 4; ++k) { s += v[10 + k] - v[k - 1]; se[k] = s; }
    }

    const float inv_n   = 1.0f / 363.0f;
    const float inv_nm1 = 1.0f / 362.0f;
    const float c1 = 1e-4f, c2 = 9e-4f;
    float local = 0.f;
    #pragma unroll
    for (int k = 0; k < 4; ++k) {
        const float s0 = sab[k].x, s1 = sab[k].y;
        const float s2 = scd[k].x, s3 = scd[k].y, s4 = se[k];
        const float mu_p  = s0 * inv_n;
        const float mu_g  = s1 * inv_n;
        const float var_p = (s2 - s0 * mu_p) * inv_nm1;
        const float var_g = (s3 - s1 * mu_g) * inv_nm1;
        const float cov   = (s4 - s0 * mu_g) * inv_n;
        const float num = (2.f * mu_p * mu_g + c1) * (2.f * cov + c2);
        const float den = (mu_p * mu_p + mu_g * mu_g + c1) * (var_p + var_g + c2);
        local += num / (den + 1e-8f);
    }

    // ---- Block reduce ----
    #pragma unroll
    for (int off = 32; off > 0; off >>= 1) local += __shfl_down(local, off);
    if ((tid & 63) == 0) red[tid >> 6] = local;
    __syncthreads();
    if (tid == 0) partial[bid] = red[0] + red[1] + red[2] + red[3];
}

__global__ __launch_bounds__(256) void ssim_final_reduce(
    const float* __restrict__ partial, float* __restrict__ out)
{
    __shared__ float red[4];
    const int tid = threadIdx.x;
    float s = 0.f;
    for (int i = tid; i < NBLOCKS; i += 256) s += partial[i];
    #pragma unroll
    for (int off = 32; off > 0; off >>= 1) s += __shfl_down(s, off);
    if ((tid & 63) == 0) red[tid >> 6] = s;
    __syncthreads();
    if (tid == 0) {
        const float total = red[0] + red[1] + red[2] + red[3];
        out[0] = 1.0f - total * (1.0f / (float)(BATCH * H * W));
    }
}

extern "C" void kernel_launch(void* const* d_in, const int* in_sizes, int n_in,
                              void* d_out, int out_size, void* d_ws, size_t ws_size,
                              hipStream_t stream) {
    const float* pred = (const float*)d_in[0];
    const float* gt   = (const float*)d_in[1];
    float* out        = (float*)d_out;
    float* partial    = (float*)d_ws;

    ssim_tile_kernel<<<NBLOCKS, 256, 0, stream>>>(pred, gt, partial);
    ssim_final_reduce<<<1, 256, 0, stream>>>(partial, out);
}